// Round 4
// baseline (294.491 us; speedup 1.0000x reference)
//
#include <hip/hip_runtime.h>

// Problem constants (fixed by the reference)
#define NN    100000   // nodes
#define NE    3200000  // edges
#define DIMK  256      // feature dim
#define NC    32       // classes
#define NG    64       // graphs

#define ROWS   64      // nodes per src-bucket (A-chunk rows)
#define NBUCK  1563    // ceil(NN / 64)
#define NBUCKP 1564    // padded bucket count (scan divisibility)
#define NB1    512     // edge-chunk blocks for bucketing (NE/NB1 = 6250 exact)
#define EPB    6250    // edges per bucketing block
#define NSCAN  782     // NBUCKP*NB1/1024 = 800768/1024 = 782 exact
#define NSL    16      // reduce slices

// Workspace layout (bytes). Records (12.8 MB) overlay deg partials (12.8 MB):
// deg partials are dead before k_place writes records.
static constexpr size_t OFF_REC    = 0;           // [NE] u32 = 12,800,000 (also 256*12500 u32 deg parts)
static constexpr size_t OFF_DEGARR = 12800000;    // [NN] u32
static constexpr size_t OFF_DINV   = 13200000;    // [NN] f32
static constexpr size_t OFF_CNT    = 13600000;    // [NBUCKP*NB1] int = 3,203,072
static constexpr size_t OFF_EXC    = 16803072;    // [NBUCKP*NB1] int
static constexpr size_t OFF_BSUM   = 20006144;    // [NSCAN] int (pad 4096)
static constexpr size_t OFF_TOPS   = 20010240;    // [NSCAN] int (pad 4096)
static constexpr size_t OFF_START  = 20014336;    // [NG+1] int (pad 512)
static constexpr size_t OFF_CTRL   = 20014848;    // int[2]: {i64 flag, work counter} (pad 128)
static constexpr size_t OFF_P2     = 20014976;    // [NSL][NG*DIMK] f32 = 1,048,576
static constexpr size_t OFF_PART   = 21063552;    // [grid][NG*DIMK] f32

__device__ __forceinline__ int idx_at(const void* p, long i, bool i64) {
    return i64 ? (int)((const long long*)p)[i] : ((const int*)p)[i];
}

// int64 vs int32 detection (high words of first int64 entries all zero) + zero
// the persistent-block work counter.
__global__ void k_detect(const int* __restrict__ ei_raw, int* __restrict__ ctrl) {
    int z = (ei_raw[1] == 0) + (ei_raw[3] == 0) + (ei_raw[5] == 0) +
            (ei_raw[7] == 0) + (ei_raw[9] == 0) + (ei_raw[11] == 0);
    ctrl[0] = (z == 6) ? 1 : 0;
    ctrl[1] = 0;
}

// LDS-privatized degree histogram (u8 counters; max degree ~70 << 255).
// Block b: half hh=b>>7 (node range 50000), slice sl=b&127 (25000 edges).
__global__ __launch_bounds__(256) void k_deg_hist(const void* __restrict__ ei,
        unsigned int* __restrict__ parts, const int* __restrict__ ctrl) {
    __shared__ unsigned int h[12500];   // 50 KB: 50000 u8 counters
    const bool i64 = ctrl[0] != 0;
    const int b = blockIdx.x;
    const int hh = b >> 7;
    const int sl = b & 127;
    const int lo = hh * 50000, hi = lo + 50000;
    for (int t = threadIdx.x; t < 12500; t += 256) h[t] = 0u;
    __syncthreads();
    const int e0 = sl * 25000;
    for (int e = e0 + threadIdx.x; e < e0 + 25000; e += 256) {
        int d = idx_at(ei, (long)NE + e, i64);
        if (d >= lo && d < hi) {
            int r = d - lo;
            atomicAdd(&h[r >> 2], 1u << ((r & 3) * 8));
        }
    }
    __syncthreads();
    for (int t = threadIdx.x; t < 12500; t += 256)
        parts[(size_t)b * 12500 + t] = h[t];
}

// Merged node-level pass: blocks 0..97 reduce the degree histogram into
// degarr/dinv; blocks 98..488 compute graph start offsets from sorted batch.
__global__ void k_node(const unsigned int* __restrict__ parts,
                       unsigned int* __restrict__ degarr, float* __restrict__ dinv,
                       const void* __restrict__ batch, int* __restrict__ start,
                       const int* __restrict__ ctrl) {
    const int b = blockIdx.x;
    if (b < 98) {
        int i = b * 256 + threadIdx.x;   // word index, 0..24999
        if (i >= 25000) return;
        int h = (i >= 12500) ? 1 : 0;
        int w = i - h * 12500;
        int c0 = 0, c1 = 0, c2 = 0, c3 = 0;
        const unsigned int* base = parts + (size_t)(h * 128) * 12500 + w;
#pragma unroll 4
        for (int s = 0; s < 128; ++s) {
            unsigned int v = base[(size_t)s * 12500];
            c0 += v & 255u; c1 += (v >> 8) & 255u; c2 += (v >> 16) & 255u; c3 += v >> 24;
        }
        int node = h * 50000 + w * 4;
        degarr[node]     = 1u + c0;  dinv[node]     = 1.0f / sqrtf((float)(1 + c0));
        degarr[node + 1] = 1u + c1;  dinv[node + 1] = 1.0f / sqrtf((float)(1 + c1));
        degarr[node + 2] = 1u + c2;  dinv[node + 2] = 1.0f / sqrtf((float)(1 + c2));
        degarr[node + 3] = 1u + c3;  dinv[node + 3] = 1.0f / sqrtf((float)(1 + c3));
    } else {
        const bool i64 = ctrl[0] != 0;
        int i = (b - 98) * 256 + threadIdx.x;
        if (i >= NN) return;
        int bi = idx_at(batch, i, i64);
        int bp = (i == 0) ? -1 : idx_at(batch, i - 1, i64);
        for (int g = bp + 1; g <= bi; ++g) start[g] = i;
        if (i == NN - 1)
            for (int g = bi + 1; g <= NG; ++g) start[g] = NN;
    }
}

// Per-(bucket, block) edge counts via LDS counters. cnt_part[bucket][block].
__global__ __launch_bounds__(256) void k_bucket_count(const void* __restrict__ ei,
        int* __restrict__ cnt_part, const int* __restrict__ ctrl) {
    __shared__ unsigned int lc[NBUCKP];
    const bool i64 = ctrl[0] != 0;
    const int k = blockIdx.x;
    for (int t = threadIdx.x; t < NBUCKP; t += 256) lc[t] = 0u;
    __syncthreads();
    const int e0 = k * EPB;
    for (int e = e0 + threadIdx.x; e < e0 + EPB; e += 256) {
        int s = idx_at(ei, e, i64);
        atomicAdd(&lc[s >> 6], 1u);
    }
    __syncthreads();
    for (int t = threadIdx.x; t < NBUCKP; t += 256)
        cnt_part[t * NB1 + k] = (int)lc[t];
}

// Exclusive scan, stage 1: per-1024-chunk scan + chunk sums.
__global__ void k_scan_partial(const int* __restrict__ cnt, int* __restrict__ exc,
                               int* __restrict__ bsum) {
    __shared__ int s[1024];
    int i = blockIdx.x * 1024 + threadIdx.x;
    int v = cnt[i];
    s[threadIdx.x] = v;
    __syncthreads();
    for (int off = 1; off < 1024; off <<= 1) {
        int t = (threadIdx.x >= off) ? s[threadIdx.x - off] : 0;
        __syncthreads();
        s[threadIdx.x] += t;
        __syncthreads();
    }
    exc[i] = s[threadIdx.x] - v;
    if (threadIdx.x == 1023) bsum[blockIdx.x] = s[1023];
}

// Exclusive scan, stage 2: parallel single-block scan of the 782 chunk sums.
__global__ void k_scan_tops(const int* __restrict__ bsum, int* __restrict__ tops) {
    __shared__ int s[1024];
    int t = threadIdx.x;
    int v = (t < NSCAN) ? bsum[t] : 0;
    s[t] = v;
    __syncthreads();
    for (int off = 1; off < 1024; off <<= 1) {
        int u = (t >= off) ? s[t - off] : 0;
        __syncthreads();
        s[t] += u;
        __syncthreads();
    }
    if (t < NSCAN) tops[t] = s[t] - v;
}

// Place 4-byte edge records: (deg[dst] << 13) | ((src&63)*64 + batch[dst]).
__global__ __launch_bounds__(256) void k_place(const void* __restrict__ ei,
        const void* __restrict__ batch, const unsigned int* __restrict__ degarr,
        const int* __restrict__ exc, const int* __restrict__ tops,
        unsigned int* __restrict__ rec, const int* __restrict__ ctrl) {
    __shared__ unsigned int lc[NBUCKP];
    __shared__ int lbase[NBUCKP];
    const bool i64 = ctrl[0] != 0;
    const int k = blockIdx.x;
    for (int t = threadIdx.x; t < NBUCKP; t += 256) {
        lc[t] = 0u;
        int ii = t * NB1 + k;
        lbase[t] = exc[ii] + tops[ii >> 10];
    }
    __syncthreads();
    const int e0 = k * EPB;
    for (int e = e0 + threadIdx.x; e < e0 + EPB; e += 256) {
        int s = idx_at(ei, e, i64);
        int d = idx_at(ei, (long)NE + e, i64);
        int g = idx_at(batch, d, i64);
        unsigned int deg = min(degarr[d], 524287u);
        int b = s >> 6;
        unsigned int r = atomicAdd(&lc[b], 1u);
        rec[lbase[b] + (int)r] = (deg << 13) | (unsigned)((s & 63) * 64 + g);
    }
}

// Fused persistent kernel: work-steal buckets via atomic counter. Per bucket:
// build A'-chunk in LDS (records via LDS atomics; row jl seeded with self-loop
// dinv[j] at col batch[j]), then accumulate
// S_part[g][d] += A'[jl][g] * (dinv[j] * x[j][d]) via register outer products.
// Thread (gi,di) covers graphs gi*8..+8 and features {di*4+q, 128+di*4+q}.
__global__ __launch_bounds__(256) void k_fused(
        const float* __restrict__ x, const float* __restrict__ dinv,
        const void* __restrict__ batch, const unsigned int* __restrict__ rec,
        const int* __restrict__ exc, const int* __restrict__ tops,
        float* __restrict__ part, int* __restrict__ ctrl) {
    __shared__ __align__(16) float Ach[ROWS * 64];   // 16 KB
    __shared__ __align__(16) float xs[16][DIMK];     // 16 KB
    __shared__ int sbkt;
    const bool i64 = ctrl[0] != 0;
    const int tid = threadIdx.x;
    const int gi = tid >> 5;    // graph group 0..7
    const int di = tid & 31;    // feature lane

    float acc[8][8];
#pragma unroll
    for (int g = 0; g < 8; ++g)
#pragma unroll
        for (int k = 0; k < 8; ++k) acc[g][k] = 0.0f;

    for (;;) {
        if (tid == 0) sbkt = atomicAdd(&ctrl[1], 1);
        __syncthreads();
        const int bkt = sbkt;
        if (bkt >= NBUCK) break;
        const int j0 = bkt * ROWS;
        for (int t = tid; t < ROWS * 64; t += 256) Ach[t] = 0.0f;
        __syncthreads();
        if (tid < ROWS) {
            int j = j0 + tid;
            if (j < NN) Ach[tid * 64 + idx_at(batch, j, i64)] = dinv[j];
        }
        __syncthreads();
        const int ia = bkt * NB1;
        const int ib = ia + NB1;
        const int rbeg = exc[ia] + tops[ia >> 10];
        const int rend = exc[ib] + tops[ib >> 10];
        for (int r = rbeg + tid; r < rend; r += 256) {
            unsigned int q = rec[r];
            float val = 1.0f / sqrtf((float)(q >> 13));   // bit-identical to dinv[]
            atomicAdd(&Ach[q & 4095u], val);
        }
        __syncthreads();

        for (int c0 = 0; c0 < ROWS; c0 += 16) {
            for (int t = tid; t < 16 * 64; t += 256) {
                int jj = t >> 6, d4 = t & 63;
                int j = j0 + c0 + jj;
                float4 v = make_float4(0.f, 0.f, 0.f, 0.f);
                if (j < NN) {
                    float dv = dinv[j];
                    float4 u = ((const float4*)x)[(size_t)j * 64 + d4];
                    v.x = dv * u.x; v.y = dv * u.y; v.z = dv * u.z; v.w = dv * u.w;
                }
                ((float4*)xs[jj])[d4] = v;
            }
            __syncthreads();
#pragma unroll
            for (int jj = 0; jj < 16; ++jj) {
                const float* arow = &Ach[(c0 + jj) * 64 + gi * 8];
                float4 p0 = *(const float4*)arow;            // broadcast per half-wave
                float4 p1 = *(const float4*)(arow + 4);
                const float4* xr = (const float4*)xs[jj];
                float4 a0 = xr[di];                          // features di*4..+4
                float4 a1 = xr[di + 32];                     // features 128+di*4..+4
                float pg[8] = {p0.x, p0.y, p0.z, p0.w, p1.x, p1.y, p1.z, p1.w};
                float xv[8] = {a0.x, a0.y, a0.z, a0.w, a1.x, a1.y, a1.z, a1.w};
#pragma unroll
                for (int g = 0; g < 8; ++g)
#pragma unroll
                    for (int k = 0; k < 8; ++k)
                        acc[g][k] = fmaf(pg[g], xv[k], acc[g][k]);
            }
            __syncthreads();
        }
    }

    // write block partial (blocks with no work write zeros)
    float* p = part + (size_t)blockIdx.x * (NG * DIMK);
#pragma unroll
    for (int g = 0; g < 8; ++g) {
        int gg = gi * 8 + g;
        float4 w0 = make_float4(acc[g][0], acc[g][1], acc[g][2], acc[g][3]);
        float4 w1 = make_float4(acc[g][4], acc[g][5], acc[g][6], acc[g][7]);
        ((float4*)(p + gg * DIMK))[di] = w0;
        ((float4*)(p + gg * DIMK + 128))[di] = w1;
    }
}

// Split-K reduce stage 1: NSL b-slices x 4096 float4 cols, coalesced.
__global__ __launch_bounds__(256) void k_reduce1(const float4* __restrict__ part,
        float4* __restrict__ p2, int nblk) {
    int id = blockIdx.x * 256 + threadIdx.x;   // 0..65535
    int c4 = id & 4095;
    int sl = id >> 12;
    int span = (nblk + NSL - 1) / NSL;
    int b0 = sl * span, b1 = min(b0 + span, nblk);
    float4 s = make_float4(0.f, 0.f, 0.f, 0.f);
    for (int b = b0; b < b1; ++b) {
        float4 v = part[(size_t)b * 4096 + c4];
        s.x += v.x; s.y += v.y; s.z += v.z; s.w += v.w;
    }
    p2[(size_t)sl * 4096 + c4] = s;
}

// Final: fold NSL slices into S (LDS), then S @ W / cnt + bias.
__global__ __launch_bounds__(256) void k_final(const float* __restrict__ p2,
        const float* __restrict__ W, const float* __restrict__ bias,
        const int* __restrict__ start, float* __restrict__ out) {
    __shared__ float Sb[8 * DIMK];   // 8 KB
    const int tid = threadIdx.x, b = blockIdx.x;
    for (int t = tid; t < 8 * DIMK; t += 256) {
        int gl = t >> 8, d = t & 255;
        float s = 0.f;
#pragma unroll
        for (int sl = 0; sl < NSL; ++sl)
            s += p2[(size_t)sl * (NG * DIMK) + (b * 8 + gl) * DIMK + d];
        Sb[t] = s;
    }
    __syncthreads();
    int g = tid >> 5, c = tid & 31;
    float sum = 0.f;
#pragma unroll 8
    for (int d = 0; d < DIMK; ++d)
        sum = fmaf(Sb[g * DIMK + d], W[d * NC + c], sum);
    int gg = b * 8 + g;
    float cn = (float)max(start[gg + 1] - start[gg], 1);
    out[gg * NC + c] = sum / cn + bias[c];
}

extern "C" void kernel_launch(void* const* d_in, const int* in_sizes, int n_in,
                              void* d_out, int out_size, void* d_ws, size_t ws_size,
                              hipStream_t stream) {
    const float* x    = (const float*)d_in[0];
    const float* W    = (const float*)d_in[1];
    const float* bias = (const float*)d_in[2];
    const void*  ei   = d_in[3];
    const void*  batch= d_in[4];
    float* out = (float*)d_out;

    char* ws = (char*)d_ws;
    unsigned int* rec  = (unsigned int*)(ws + OFF_REC);
    unsigned int* degp = (unsigned int*)(ws + OFF_REC);   // overlay (dead before rec)
    unsigned int* degarr = (unsigned int*)(ws + OFF_DEGARR);
    float* dinv  = (float*)(ws + OFF_DINV);
    int*   cntp  = (int*)(ws + OFF_CNT);
    int*   exc   = (int*)(ws + OFF_EXC);
    int*   bsum  = (int*)(ws + OFF_BSUM);
    int*   tops  = (int*)(ws + OFF_TOPS);
    int*   start = (int*)(ws + OFF_START);
    int*   ctrl  = (int*)(ws + OFF_CTRL);
    float* p2    = (float*)(ws + OFF_P2);
    float* part  = (float*)(ws + OFF_PART);

    int grid = 256;   // safe floor (needs 37.8 MB; round-3 proved >= 43.5 MB)
    if      (ws_size >= OFF_PART + 1024ull * NG * DIMK * 4) grid = 1024;
    else if (ws_size >= OFF_PART +  512ull * NG * DIMK * 4) grid = 512;

    k_detect      <<<1, 1, 0, stream>>>((const int*)ei, ctrl);
    k_deg_hist    <<<256, 256, 0, stream>>>(ei, degp, ctrl);
    k_node        <<<489, 256, 0, stream>>>(degp, degarr, dinv, batch, start, ctrl);
    k_bucket_count<<<NB1, 256, 0, stream>>>(ei, cntp, ctrl);
    k_scan_partial<<<NSCAN, 1024, 0, stream>>>(cntp, exc, bsum);
    k_scan_tops   <<<1, 1024, 0, stream>>>(bsum, tops);
    k_place       <<<NB1, 256, 0, stream>>>(ei, batch, degarr, exc, tops, rec, ctrl);
    k_fused       <<<grid, 256, 0, stream>>>(x, dinv, batch, rec, exc, tops, part, ctrl);
    k_reduce1     <<<256, 256, 0, stream>>>((const float4*)part, (float4*)p2, grid);
    k_final       <<<8, 256, 0, stream>>>(p2, W, bias, start, out);
}